// Round 2
// baseline (275.277 us; speedup 1.0000x reference)
//
#include <hip/hip_runtime.h>
#include <math.h>

#define NN 1024
#define FF 32
#define EE 20
#define TJ 64      // j-tile per LDS stage
#define NI 2       // rows (i) per block
#define NODE_STRIDE 160   // P[96] | leftB[32] | leftC[32]

__device__ __forceinline__ float silu_f(float x) {
    return x / (1.0f + __expf(-x));
}

// ---------------------------------------------------------------------------
// Kernel 1: per-node precompute.
//   left[j,0:96] = silu(s[j]@mL_w1+b1)@mL_w2+b2
//   node[j] = [ P(96)=v[j,d,f]*leftA[j,f] | leftB(32) | leftC(32) ]
// ---------------------------------------------------------------------------
extern "C" __global__ __launch_bounds__(128)
void node_kernel(const float* __restrict__ scalar,
                 const float* __restrict__ vector,
                 const float* __restrict__ mL_w1, const float* __restrict__ mL_b1,
                 const float* __restrict__ mL_w2, const float* __restrict__ mL_b2,
                 float* __restrict__ node)
{
    const int j = blockIdx.x;
    const int t = threadIdx.x;
    __shared__ float ss[32], sh[32], sleft[96];

    if (t < 32) ss[t] = scalar[j * 32 + t];
    __syncthreads();
    if (t < 32) {
        float a = mL_b1[t];
        #pragma unroll
        for (int k = 0; k < 32; k++) a = fmaf(ss[k], mL_w1[k * 32 + t], a);
        sh[t] = silu_f(a);
    }
    __syncthreads();
    if (t < 96) {
        float a = mL_b2[t];
        #pragma unroll
        for (int k = 0; k < 32; k++) a = fmaf(sh[k], mL_w2[k * 96 + t], a);
        sleft[t] = a;
    }
    __syncthreads();
    if (t < 96) {
        node[j * NODE_STRIDE + t] = vector[j * 96 + t] * sleft[t & 31];
    } else {
        const int f = t - 96;   // 0..31
        node[j * NODE_STRIDE + 96 + f]  = sleft[32 + f];
        node[j * NODE_STRIDE + 128 + f] = sleft[64 + f];
    }
}

// ---------------------------------------------------------------------------
// Kernel 2: edge reduction (message) + fused update, NI rows per block.
// ---------------------------------------------------------------------------
extern "C" __global__ __launch_bounds__(256)
void edge_kernel(const float* __restrict__ scalar,
                 const float* __restrict__ vector,
                 const float* __restrict__ expansion,
                 const float* __restrict__ direction,
                 const float* __restrict__ mask,
                 const float* __restrict__ mR_w, const float* __restrict__ mR_b,
                 const float* __restrict__ uR_w1, const float* __restrict__ uR_b1,
                 const float* __restrict__ uR_w2, const float* __restrict__ uR_b2,
                 const float* __restrict__ U_w,  const float* __restrict__ V_w,
                 const float* __restrict__ node,
                 float* __restrict__ out)
{
    const int t = threadIdx.x;
    const int group = t >> 5;      // 0..7
    const int f = t & 31;
    const int i0 = blockIdx.x * NI;

    __shared__ float sE[NI * TJ * 24];      // per (r,j): exp[20] dir[3] mask
    __shared__ float sred[256 * 4];
    __shared__ float snew[32], vnew[96];
    __shared__ float lU[96], rV[96], rnorm[32], h2[32], f2[96];

    // mR_w columns for this f into registers
    float WA[20], WB[20], WC[20];
    #pragma unroll
    for (int e = 0; e < 20; e++) {
        WA[e] = mR_w[e * 96 + f];
        WB[e] = mR_w[e * 96 + 32 + f];
        WC[e] = mR_w[e * 96 + 64 + f];
    }
    const float bA = mR_b[f], bB = mR_b[32 + f], bC = mR_b[64 + f];

    float accS[NI], accV0[NI], accV1[NI], accV2[NI];
    #pragma unroll
    for (int r = 0; r < NI; r++) { accS[r] = 0.f; accV0[r] = 0.f; accV1[r] = 0.f; accV2[r] = 0.f; }

    for (int tile = 0; tile < NN / TJ; ++tile) {
        __syncthreads();
        // stage exp: NI*320 float4 (20 % 4 == 0, so float4 never crosses a j)
        for (int idx = t; idx < NI * 320; idx += 256) {
            const int r = idx / 320, q = idx - r * 320;
            const float4 v = *reinterpret_cast<const float4*>(
                expansion + ((size_t)(i0 + r) * NN + tile * TJ) * 20 + q * 4);
            const int jl = q / 5, c = (q - jl * 5) * 4;
            *reinterpret_cast<float4*>(&sE[(r * TJ + jl) * 24 + c]) = v;
        }
        // stage dir: NI*192 scalars
        for (int idx = t; idx < NI * 192; idx += 256) {
            const int r = idx / 192, q = idx - r * 192;
            const int jl = q / 3, d = q - jl * 3;
            sE[(r * TJ + jl) * 24 + 20 + d] =
                direction[((size_t)(i0 + r) * NN + tile * TJ) * 3 + q];
        }
        // stage mask: NI*TJ
        if (t < NI * TJ) {
            const int r = t / TJ, jl = t - r * TJ;
            sE[(r * TJ + jl) * 24 + 23] = mask[(size_t)(i0 + r) * NN + tile * TJ + jl];
        }
        __syncthreads();

        for (int q8 = 0; q8 < TJ / 8; ++q8) {
            const int jl = group * (TJ / 8) + q8;
            const int jg = tile * TJ + jl;
            const float* nd = node + (size_t)jg * NODE_STRIDE;
            const float P0 = nd[f],      P1 = nd[32 + f], P2 = nd[64 + f];
            const float lB = nd[96 + f], lC = nd[128 + f];
            #pragma unroll
            for (int r = 0; r < NI; ++r) {
                const float4* eb = reinterpret_cast<const float4*>(&sE[(r * TJ + jl) * 24]);
                const float4 e0 = eb[0], e1 = eb[1], e2 = eb[2], e3 = eb[3], e4 = eb[4];
                const float4 dm = eb[5];
                float ex[20];
                ex[0]=e0.x; ex[1]=e0.y; ex[2]=e0.z; ex[3]=e0.w;
                ex[4]=e1.x; ex[5]=e1.y; ex[6]=e1.z; ex[7]=e1.w;
                ex[8]=e2.x; ex[9]=e2.y; ex[10]=e2.z; ex[11]=e2.w;
                ex[12]=e3.x; ex[13]=e3.y; ex[14]=e3.z; ex[15]=e3.w;
                ex[16]=e4.x; ex[17]=e4.y; ex[18]=e4.z; ex[19]=e4.w;
                float rA = bA, rB = bB, rC = bC;
                #pragma unroll
                for (int e = 0; e < 20; e++) {
                    rA = fmaf(ex[e], WA[e], rA);
                    rB = fmaf(ex[e], WB[e], rB);
                    rC = fmaf(ex[e], WC[e], rC);
                }
                const float m = dm.w;
                accS[r] = fmaf(m * lB, rB, accS[r]);
                const float rAm = rA * m;
                const float tC = lC * rC * m;
                accV0[r] = fmaf(P0, rAm, fmaf(dm.x, tC, accV0[r]));
                accV1[r] = fmaf(P1, rAm, fmaf(dm.y, tC, accV1[r]));
                accV2[r] = fmaf(P2, rAm, fmaf(dm.z, tC, accV2[r]));
            }
        }
    }

    // ------------- per-row: reduce across groups, then update phase ---------
    for (int r = 0; r < NI; ++r) {
        const int i = i0 + r;
        __syncthreads();
        sred[t * 4 + 0] = accS[r];
        sred[t * 4 + 1] = accV0[r];
        sred[t * 4 + 2] = accV1[r];
        sred[t * 4 + 3] = accV2[r];
        __syncthreads();
        if (t < 128) {
            const int d = t >> 5, ff = t & 31;
            float a = 0.f;
            #pragma unroll
            for (int g = 0; g < 8; g++) a += sred[((g << 5) | ff) * 4 + d];
            if (d == 0) snew[ff] = scalar[i * 32 + ff] + a;
            else        vnew[(d - 1) * 32 + ff] = vector[i * 96 + (d - 1) * 32 + ff] + a;
        }
        __syncthreads();

        // lU = vnew@U_w ; rV = vnew@V_w
        if (t < 96) {
            const int d = t >> 5, ff = t & 31;
            float a = 0.0f;
            #pragma unroll
            for (int k = 0; k < 32; k++) a = fmaf(vnew[d * 32 + k], U_w[k * 32 + ff], a);
            lU[t] = a;
        } else if (t >= 128 && t < 224) {
            const int dt = t - 128, d = dt >> 5, ff = dt & 31;
            float a = 0.0f;
            #pragma unroll
            for (int k = 0; k < 32; k++) a = fmaf(vnew[d * 32 + k], V_w[k * 32 + ff], a);
            rV[dt] = a;
        }
        __syncthreads();
        if (t < 32) {
            const float a = rV[t] * rV[t] + rV[32 + t] * rV[32 + t] + rV[64 + t] * rV[64 + t];
            rnorm[t] = sqrtf(a);
        }
        __syncthreads();
        if (t < 32) {
            float a = uR_b1[t];
            #pragma unroll
            for (int k = 0; k < 32; k++) a = fmaf(snew[k],  uR_w1[k * 32 + t], a);
            #pragma unroll
            for (int k = 0; k < 32; k++) a = fmaf(rnorm[k], uR_w1[(32 + k) * 32 + t], a);
            h2[t] = silu_f(a);
        }
        __syncthreads();
        if (t < 96) {
            float a = uR_b2[t];
            #pragma unroll
            for (int k = 0; k < 32; k++) a = fmaf(h2[k], uR_w2[k * 96 + t], a);
            f2[t] = a;
        }
        __syncthreads();
        if (t < 32) {
            const float inner = lU[t] * rV[t] + lU[32 + t] * rV[32 + t] + lU[64 + t] * rV[64 + t];
            out[i * 32 + t] = snew[t] + inner * f2[32 + t] + f2[64 + t];
        } else if (t >= 64 && t < 160) {
            const int dt = t - 64, ff = dt & 31;
            out[32768 + i * 96 + dt] = vnew[dt] + f2[ff] * lU[dt];
        }
    }
}

extern "C" void kernel_launch(void* const* d_in, const int* in_sizes, int n_in,
                              void* d_out, int out_size, void* d_ws, size_t ws_size,
                              hipStream_t stream) {
    const float* scalar    = (const float*)d_in[0];
    const float* vector    = (const float*)d_in[1];
    const float* expansion = (const float*)d_in[2];
    const float* direction = (const float*)d_in[3];
    const float* mask      = (const float*)d_in[4];
    const float* mL_w1     = (const float*)d_in[5];
    const float* mL_b1     = (const float*)d_in[6];
    const float* mL_w2     = (const float*)d_in[7];
    const float* mL_b2     = (const float*)d_in[8];
    const float* mR_w      = (const float*)d_in[9];
    const float* mR_b      = (const float*)d_in[10];
    const float* uR_w1     = (const float*)d_in[11];
    const float* uR_b1     = (const float*)d_in[12];
    const float* uR_w2     = (const float*)d_in[13];
    const float* uR_b2     = (const float*)d_in[14];
    const float* U_w       = (const float*)d_in[15];
    const float* V_w       = (const float*)d_in[16];
    float* out = (float*)d_out;
    float* node = (float*)d_ws;   // 1024 * 160 * 4 = 640 KB

    hipLaunchKernelGGL(node_kernel, dim3(NN), dim3(128), 0, stream,
                       scalar, vector, mL_w1, mL_b1, mL_w2, mL_b2, node);
    hipLaunchKernelGGL(edge_kernel, dim3(NN / NI), dim3(256), 0, stream,
                       scalar, vector, expansion, direction, mask,
                       mR_w, mR_b, uR_w1, uR_b1, uR_w2, uR_b2, U_w, V_w,
                       node, out);
}

// Round 3
// 225.886 us; speedup vs baseline: 1.2187x; 1.2187x over previous
//
#include <hip/hip_runtime.h>
#include <math.h>

#define NN 1024
#define FF 32
#define EE 20
#define TJ 64        // j-tile per LDS stage
#define NI 2         // rows (i) per block
#define JSPLIT 2     // j-range split across blocks
#define NODE_STRIDE 160   // P[96] | leftB[32] | leftC[32]

__device__ __forceinline__ float silu_f(float x) {
    return x / (1.0f + __expf(-x));
}

// ---------------------------------------------------------------------------
// Kernel 1: per-node precompute.
//   left[j,0:96] = silu(s[j]@mL_w1+b1)@mL_w2+b2
//   node[j] = [ P(96)=v[j,d,f]*leftA[j,f] | leftB(32) | leftC(32) ]
// ---------------------------------------------------------------------------
extern "C" __global__ __launch_bounds__(128)
void node_kernel(const float* __restrict__ scalar,
                 const float* __restrict__ vector,
                 const float* __restrict__ mL_w1, const float* __restrict__ mL_b1,
                 const float* __restrict__ mL_w2, const float* __restrict__ mL_b2,
                 float* __restrict__ node)
{
    const int j = blockIdx.x;
    const int t = threadIdx.x;
    __shared__ float ss[32], sh[32], sleft[96];

    if (t < 32) ss[t] = scalar[j * 32 + t];
    __syncthreads();
    if (t < 32) {
        float a = mL_b1[t];
        #pragma unroll
        for (int k = 0; k < 32; k++) a = fmaf(ss[k], mL_w1[k * 32 + t], a);
        sh[t] = silu_f(a);
    }
    __syncthreads();
    if (t < 96) {
        float a = mL_b2[t];
        #pragma unroll
        for (int k = 0; k < 32; k++) a = fmaf(sh[k], mL_w2[k * 96 + t], a);
        sleft[t] = a;
    }
    __syncthreads();
    if (t < 96) {
        node[j * NODE_STRIDE + t] = vector[j * 96 + t] * sleft[t & 31];
    } else {
        const int f = t - 96;   // 0..31
        node[j * NODE_STRIDE + 96 + f]  = sleft[32 + f];
        node[j * NODE_STRIDE + 128 + f] = sleft[64 + f];
    }
}

// ---------------------------------------------------------------------------
// Kernel 2: edge reduction over a half j-range; writes 128-float partial
// per (row, jhalf) to ws.
// ---------------------------------------------------------------------------
extern "C" __global__ __launch_bounds__(256)
void edge_kernel(const float* __restrict__ expansion,
                 const float* __restrict__ direction,
                 const float* __restrict__ mask,
                 const float* __restrict__ mR_w, const float* __restrict__ mR_b,
                 const float* __restrict__ node,
                 float* __restrict__ partial)
{
    const int t = threadIdx.x;
    const int group = t >> 5;      // 0..7
    const int f = t & 31;
    const int ipair = blockIdx.x >> 1;
    const int jhalf = blockIdx.x & 1;
    const int i0 = ipair * NI;

    __shared__ float sEx[NI * TJ * 20];   // straight-copy exp
    __shared__ float sD[NI * TJ * 3];     // straight-copy dir
    __shared__ float sM[NI * TJ];         // mask
    __shared__ float sred[256 * 4];

    // mR_w columns for this f into registers
    float WA[20], WB[20], WC[20];
    #pragma unroll
    for (int e = 0; e < 20; e++) {
        WA[e] = mR_w[e * 96 + f];
        WB[e] = mR_w[e * 96 + 32 + f];
        WC[e] = mR_w[e * 96 + 64 + f];
    }
    const float bA = mR_b[f], bB = mR_b[32 + f], bC = mR_b[64 + f];

    float accS[NI], accV0[NI], accV1[NI], accV2[NI];
    #pragma unroll
    for (int r = 0; r < NI; r++) { accS[r] = 0.f; accV0[r] = 0.f; accV1[r] = 0.f; accV2[r] = 0.f; }

    for (int tt = 0; tt < NN / TJ / JSPLIT; ++tt) {
        const int j0 = (jhalf * (NN / TJ / JSPLIT) + tt) * TJ;
        __syncthreads();
        // stage exp: per r, 320 float4, straight copy (no repack, no int div)
        #pragma unroll
        for (int r = 0; r < NI; ++r) {
            const float4* src = reinterpret_cast<const float4*>(
                expansion + ((size_t)(i0 + r) * NN + j0) * 20);
            float4* dst = reinterpret_cast<float4*>(&sEx[r * TJ * 20]);
            for (int q = t; q < TJ * 5; q += 256) dst[q] = src[q];
        }
        // stage dir: per r, 48 float4
        if (t < 96) {
            const int r = (t >= 48) ? 1 : 0;
            const int q = t - 48 * r;
            const float4* src = reinterpret_cast<const float4*>(
                direction + ((size_t)(i0 + r) * NN + j0) * 3);
            reinterpret_cast<float4*>(&sD[r * TJ * 3])[q] = src[q];
        }
        // stage mask: per r, 16 float4
        if (t < 32) {
            const int r = t >> 4, q = t & 15;
            const float4* src = reinterpret_cast<const float4*>(
                mask + (size_t)(i0 + r) * NN + j0);
            reinterpret_cast<float4*>(&sM[r * TJ])[q] = src[q];
        }
        __syncthreads();

        for (int q8 = 0; q8 < TJ / 8; ++q8) {
            const int jl = group * (TJ / 8) + q8;
            const int jg = j0 + jl;
            const float* nd = node + (size_t)jg * NODE_STRIDE;
            const float P0 = nd[f],      P1 = nd[32 + f], P2 = nd[64 + f];
            const float lB = nd[96 + f], lC = nd[128 + f];
            #pragma unroll
            for (int r = 0; r < NI; ++r) {
                const float4* eb = reinterpret_cast<const float4*>(&sEx[(r * TJ + jl) * 20]);
                const float4 e0 = eb[0], e1 = eb[1], e2 = eb[2], e3 = eb[3], e4 = eb[4];
                float ex[20];
                ex[0]=e0.x; ex[1]=e0.y; ex[2]=e0.z; ex[3]=e0.w;
                ex[4]=e1.x; ex[5]=e1.y; ex[6]=e1.z; ex[7]=e1.w;
                ex[8]=e2.x; ex[9]=e2.y; ex[10]=e2.z; ex[11]=e2.w;
                ex[12]=e3.x; ex[13]=e3.y; ex[14]=e3.z; ex[15]=e3.w;
                ex[16]=e4.x; ex[17]=e4.y; ex[18]=e4.z; ex[19]=e4.w;
                float rA = bA, rB = bB, rC = bC;
                #pragma unroll
                for (int e = 0; e < 20; e++) {
                    rA = fmaf(ex[e], WA[e], rA);
                    rB = fmaf(ex[e], WB[e], rB);
                    rC = fmaf(ex[e], WC[e], rC);
                }
                const float d0 = sD[(r * TJ + jl) * 3 + 0];
                const float d1 = sD[(r * TJ + jl) * 3 + 1];
                const float d2 = sD[(r * TJ + jl) * 3 + 2];
                const float m  = sM[r * TJ + jl];
                accS[r] = fmaf(m * lB, rB, accS[r]);
                const float rAm = rA * m;
                const float tC = lC * rC * m;
                accV0[r] = fmaf(P0, rAm, fmaf(d0, tC, accV0[r]));
                accV1[r] = fmaf(P1, rAm, fmaf(d1, tC, accV1[r]));
                accV2[r] = fmaf(P2, rAm, fmaf(d2, tC, accV2[r]));
            }
        }
    }

    // cross-group reduce -> 128-float partial per row
    for (int r = 0; r < NI; ++r) {
        __syncthreads();
        sred[t * 4 + 0] = accS[r];
        sred[t * 4 + 1] = accV0[r];
        sred[t * 4 + 2] = accV1[r];
        sred[t * 4 + 3] = accV2[r];
        __syncthreads();
        if (t < 128) {
            const int d = t >> 5, ff = t & 31;
            float a = 0.f;
            #pragma unroll
            for (int g = 0; g < 8; g++) a += sred[((g << 5) | ff) * 4 + d];
            partial[(((size_t)(i0 + r)) * JSPLIT + jhalf) * 128 + t] = a;
        }
    }
}

// ---------------------------------------------------------------------------
// Kernel 3: combine partials + update phase, one block per row.
// ---------------------------------------------------------------------------
extern "C" __global__ __launch_bounds__(256)
void combine_kernel(const float* __restrict__ scalar,
                    const float* __restrict__ vector,
                    const float* __restrict__ uR_w1, const float* __restrict__ uR_b1,
                    const float* __restrict__ uR_w2, const float* __restrict__ uR_b2,
                    const float* __restrict__ U_w,  const float* __restrict__ V_w,
                    const float* __restrict__ partial,
                    float* __restrict__ out)
{
    const int i = blockIdx.x;
    const int t = threadIdx.x;
    __shared__ float snew[32], vnew[96];
    __shared__ float lU[96], rV[96], rnorm[32], h2[32], f2[96];

    if (t < 128) {
        const float a = partial[((size_t)i * JSPLIT + 0) * 128 + t]
                      + partial[((size_t)i * JSPLIT + 1) * 128 + t];
        const int d = t >> 5, ff = t & 31;
        if (d == 0) snew[ff] = scalar[i * 32 + ff] + a;
        else        vnew[(d - 1) * 32 + ff] = vector[i * 96 + (d - 1) * 32 + ff] + a;
    }
    __syncthreads();

    if (t < 96) {
        const int d = t >> 5, ff = t & 31;
        float a = 0.0f;
        #pragma unroll
        for (int k = 0; k < 32; k++) a = fmaf(vnew[d * 32 + k], U_w[k * 32 + ff], a);
        lU[t] = a;
    } else if (t >= 128 && t < 224) {
        const int dt = t - 128, d = dt >> 5, ff = dt & 31;
        float a = 0.0f;
        #pragma unroll
        for (int k = 0; k < 32; k++) a = fmaf(vnew[d * 32 + k], V_w[k * 32 + ff], a);
        rV[dt] = a;
    }
    __syncthreads();
    if (t < 32) {
        const float a = rV[t] * rV[t] + rV[32 + t] * rV[32 + t] + rV[64 + t] * rV[64 + t];
        rnorm[t] = sqrtf(a);
    }
    __syncthreads();
    if (t < 32) {
        float a = uR_b1[t];
        #pragma unroll
        for (int k = 0; k < 32; k++) a = fmaf(snew[k],  uR_w1[k * 32 + t], a);
        #pragma unroll
        for (int k = 0; k < 32; k++) a = fmaf(rnorm[k], uR_w1[(32 + k) * 32 + t], a);
        h2[t] = silu_f(a);
    }
    __syncthreads();
    if (t < 96) {
        float a = uR_b2[t];
        #pragma unroll
        for (int k = 0; k < 32; k++) a = fmaf(h2[k], uR_w2[k * 96 + t], a);
        f2[t] = a;
    }
    __syncthreads();
    if (t < 32) {
        const float inner = lU[t] * rV[t] + lU[32 + t] * rV[32 + t] + lU[64 + t] * rV[64 + t];
        out[i * 32 + t] = snew[t] + inner * f2[32 + t] + f2[64 + t];
    } else if (t >= 64 && t < 160) {
        const int dt = t - 64, ff = dt & 31;
        out[32768 + i * 96 + dt] = vnew[dt] + f2[ff] * lU[dt];
    }
}

extern "C" void kernel_launch(void* const* d_in, const int* in_sizes, int n_in,
                              void* d_out, int out_size, void* d_ws, size_t ws_size,
                              hipStream_t stream) {
    const float* scalar    = (const float*)d_in[0];
    const float* vector    = (const float*)d_in[1];
    const float* expansion = (const float*)d_in[2];
    const float* direction = (const float*)d_in[3];
    const float* mask      = (const float*)d_in[4];
    const float* mL_w1     = (const float*)d_in[5];
    const float* mL_b1     = (const float*)d_in[6];
    const float* mL_w2     = (const float*)d_in[7];
    const float* mL_b2     = (const float*)d_in[8];
    const float* mR_w      = (const float*)d_in[9];
    const float* mR_b      = (const float*)d_in[10];
    const float* uR_w1     = (const float*)d_in[11];
    const float* uR_b1     = (const float*)d_in[12];
    const float* uR_w2     = (const float*)d_in[13];
    const float* uR_b2     = (const float*)d_in[14];
    const float* U_w       = (const float*)d_in[15];
    const float* V_w       = (const float*)d_in[16];
    float* out = (float*)d_out;
    float* node = (float*)d_ws;                       // 1024*160*4 = 640 KB
    float* part = (float*)d_ws + NN * NODE_STRIDE;    // 1024*2*128*4 = 1 MB

    hipLaunchKernelGGL(node_kernel, dim3(NN), dim3(128), 0, stream,
                       scalar, vector, mL_w1, mL_b1, mL_w2, mL_b2, node);
    hipLaunchKernelGGL(edge_kernel, dim3(NN / NI * JSPLIT), dim3(256), 0, stream,
                       expansion, direction, mask, mR_w, mR_b, node, part);
    hipLaunchKernelGGL(combine_kernel, dim3(NN), dim3(256), 0, stream,
                       scalar, vector, uR_w1, uR_b1, uR_w2, uR_b2, U_w, V_w,
                       part, out);
}

// Round 4
// 222.478 us; speedup vs baseline: 1.2373x; 1.0153x over previous
//
#include <hip/hip_runtime.h>
#include <hip/hip_bf16.h>
#include <math.h>

#define NN 1024

typedef __attribute__((ext_vector_type(8))) short v8s;
typedef __attribute__((ext_vector_type(4))) float v4f;

#define MFMA(a, b, c) __builtin_amdgcn_mfma_f32_16x16x32_bf16((a), (b), (c), 0, 0, 0)

static __device__ __forceinline__ float silu_f(float x) {
    return x / (1.0f + __expf(-x));
}
static __device__ __forceinline__ unsigned short f2bf(float x) {
    __hip_bfloat16 h = __float2bfloat16(x);
    unsigned short u; __builtin_memcpy(&u, &h, 2); return u;
}
static __device__ __forceinline__ unsigned pack2bf(float lo, float hi) {
    __hip_bfloat162 h = __float22bfloat162_rn(make_float2(lo, hi));
    unsigned u; __builtin_memcpy(&u, &h, 4); return u;
}

// ---------------------------------------------------------------------------
// Kernel 1: per-node precompute -> RT[160][1024] bf16 (n-major, j contiguous).
// rows 0..31: lB[f]; 32..127: P[d,f]=v[j,d,f]*lA[f]; 128..159: lC[f].
// ---------------------------------------------------------------------------
extern "C" __global__ __launch_bounds__(128)
void node_kernel(const float* __restrict__ scalar,
                 const float* __restrict__ vector,
                 const float* __restrict__ mL_w1, const float* __restrict__ mL_b1,
                 const float* __restrict__ mL_w2, const float* __restrict__ mL_b2,
                 unsigned short* __restrict__ RT)
{
    const int j = blockIdx.x;
    const int t = threadIdx.x;
    __shared__ float ss[32], sh[32], sleft[96];

    if (t < 32) ss[t] = scalar[j * 32 + t];
    __syncthreads();
    if (t < 32) {
        float a = mL_b1[t];
        #pragma unroll
        for (int k = 0; k < 32; k++) a = fmaf(ss[k], mL_w1[k * 32 + t], a);
        sh[t] = silu_f(a);
    }
    __syncthreads();
    if (t < 96) {
        float a = mL_b2[t];
        #pragma unroll
        for (int k = 0; k < 32; k++) a = fmaf(sh[k], mL_w2[k * 96 + t], a);
        sleft[t] = a;
    }
    __syncthreads();
    for (int n = t; n < 160; n += 128) {
        float val;
        if (n < 32)        val = sleft[32 + n];
        else if (n < 128)  val = vector[j * 96 + (n - 32)] * sleft[(n - 32) & 31];
        else               val = sleft[64 + (n - 128)];
        RT[(size_t)n * NN + j] = f2bf(val);
    }
}

// ---------------------------------------------------------------------------
// Kernel 2: per-i MFMA GEMMs + fused epilogue/update. One block (128 thr) per i.
// ---------------------------------------------------------------------------
extern "C" __global__ __launch_bounds__(128, 3)
void edge_mfma_kernel(const float* __restrict__ scalar,
                      const float* __restrict__ vector,
                      const float* __restrict__ expansion,
                      const float* __restrict__ direction,
                      const float* __restrict__ mask,
                      const float* __restrict__ mR_w, const float* __restrict__ mR_b,
                      const float* __restrict__ uR_w1, const float* __restrict__ uR_b1,
                      const float* __restrict__ uR_w2, const float* __restrict__ uR_b2,
                      const float* __restrict__ U_w,  const float* __restrict__ V_w,
                      const unsigned short* __restrict__ RT,
                      float* __restrict__ out)
{
    const int i = blockIdx.x;
    const int t = threadIdx.x;
    const int wave = t >> 6;
    const int lane = t & 63;
    const int lrow = lane & 15;
    const int quad = lane >> 4;

    // LHS (bf16, A-layout, 72-ushort row pitch) overlaid later by T (fp32)
    __shared__ __align__(16) char smem[24576];
    unsigned short* L1 = (unsigned short*)smem;     // [32][72] rows: m*exp_e(20), m(1), pad
    unsigned short* L2 = L1 + 32 * 72;              // [64][72] rows: m*dir_d*exp_e(60), m*dir_d(3), pad
    float* T1 = (float*)smem;                       // [32][128]
    float* T2 = T1 + 32 * 128;                      // [64][32]
    __shared__ float snew[32], vnew[96], lUs[96], rVs[96], rnorm[32], h2s[32], f2s[96];

    v4f acc[12];
    #pragma unroll
    for (int q = 0; q < 12; ++q) acc[q] = (v4f){0.f, 0.f, 0.f, 0.f};

    const int jp = t >> 2;        // 0..31 (pair of j)
    const int g  = t & 3;         // 0: mask-rows, 1..3: mask*dir_d rows
    const int jl = jp * 2;

    for (int chunk = 0; chunk < 16; ++chunk) {
        const int j0 = chunk * 64;
        // ---- build LHS chunk (all 128 threads) ----
        {
            const size_t jg = (size_t)i * NN + j0 + jl;
            const float4* ep = (const float4*)(expansion + jg * 20);
            const float m0 = mask[jg], m1 = mask[jg + 1];
            float w0, w1;
            unsigned short *Lp, *Lx;
            if (g == 0) {
                w0 = m0; w1 = m1;
                Lp = L1; Lx = L1 + 20 * 72;
            } else {
                const int d = g - 1;
                w0 = m0 * direction[jg * 3 + d];
                w1 = m1 * direction[(jg + 1) * 3 + d];
                Lp = L2 + d * 20 * 72; Lx = L2 + (60 + d) * 72;
            }
            #pragma unroll
            for (int q = 0; q < 5; ++q) {
                const float4 a = ep[q];       // row j,   e=4q..4q+3
                const float4 b = ep[5 + q];   // row j+1
                *(unsigned*)(Lp + (4 * q + 0) * 72 + jl) = pack2bf(w0 * a.x, w1 * b.x);
                *(unsigned*)(Lp + (4 * q + 1) * 72 + jl) = pack2bf(w0 * a.y, w1 * b.y);
                *(unsigned*)(Lp + (4 * q + 2) * 72 + jl) = pack2bf(w0 * a.z, w1 * b.z);
                *(unsigned*)(Lp + (4 * q + 3) * 72 + jl) = pack2bf(w0 * a.w, w1 * b.w);
            }
            *(unsigned*)(Lx + jl) = pack2bf(w0, w1);
        }
        __syncthreads();
        // ---- MFMA phase: wave0 = G1 nt0..5 (12 mfma); wave1 = G1 nt6..7 + G2 (12) ----
        #pragma unroll
        for (int s = 0; s < 2; ++s) {
            const int koff = s * 32 + quad * 8;
            const v8s a0 = *(const v8s*)(L1 + (lrow) * 72 + koff);
            const v8s a1 = *(const v8s*)(L1 + (16 + lrow) * 72 + koff);
            const unsigned short* Bp = RT + (size_t)lrow * NN + j0 + koff;
            if (wave == 0) {
                #pragma unroll
                for (int nt = 0; nt < 6; ++nt) {
                    const v8s b = *(const v8s*)(Bp + (size_t)nt * 16 * NN);
                    acc[nt]     = MFMA(a0, b, acc[nt]);
                    acc[6 + nt] = MFMA(a1, b, acc[6 + nt]);
                }
            } else {
                const v8s b6 = *(const v8s*)(Bp + (size_t)6 * 16 * NN);
                const v8s b7 = *(const v8s*)(Bp + (size_t)7 * 16 * NN);
                acc[0] = MFMA(a0, b6, acc[0]);
                acc[1] = MFMA(a0, b7, acc[1]);
                acc[2] = MFMA(a1, b6, acc[2]);
                acc[3] = MFMA(a1, b7, acc[3]);
                const v8s d0 = *(const v8s*)(Bp + (size_t)8 * 16 * NN);
                const v8s d1 = *(const v8s*)(Bp + (size_t)9 * 16 * NN);
                #pragma unroll
                for (int mt = 0; mt < 4; ++mt) {
                    const v8s c = *(const v8s*)(L2 + (mt * 16 + lrow) * 72 + koff);
                    acc[4 + mt * 2]     = MFMA(c, d0, acc[4 + mt * 2]);
                    acc[4 + mt * 2 + 1] = MFMA(c, d1, acc[4 + mt * 2 + 1]);
                }
            }
        }
        __syncthreads();
    }

    // ---- dump acc tiles to T (C/D layout: row=quad*4+r, col=lrow) ----
    if (wave == 0) {
        #pragma unroll
        for (int mt = 0; mt < 2; ++mt)
        #pragma unroll
        for (int nt = 0; nt < 6; ++nt) {
            const v4f a = acc[mt * 6 + nt];
            #pragma unroll
            for (int r = 0; r < 4; ++r)
                T1[(mt * 16 + quad * 4 + r) * 128 + nt * 16 + lrow] = a[r];
        }
    } else {
        #pragma unroll
        for (int mt = 0; mt < 2; ++mt)
        #pragma unroll
        for (int nb = 0; nb < 2; ++nb) {
            const v4f a = acc[mt * 2 + nb];
            #pragma unroll
            for (int r = 0; r < 4; ++r)
                T1[(mt * 16 + quad * 4 + r) * 128 + (6 + nb) * 16 + lrow] = a[r];
        }
        #pragma unroll
        for (int mt = 0; mt < 4; ++mt)
        #pragma unroll
        for (int nb = 0; nb < 2; ++nb) {
            const v4f a = acc[4 + mt * 2 + nb];
            #pragma unroll
            for (int r = 0; r < 4; ++r)
                T2[(mt * 16 + quad * 4 + r) * 32 + nb * 16 + lrow] = a[r];
        }
    }
    __syncthreads();

    // ---- epilogue: contract T with mR_w/mR_b ----
    if (t < 32) {
        const int f = t;
        float a = mR_b[32 + f] * T1[20 * 128 + f];
        #pragma unroll
        for (int e = 0; e < 20; ++e) a = fmaf(mR_w[e * 96 + 32 + f], T1[e * 128 + f], a);
        snew[f] = scalar[i * 32 + f] + a;
    } else if (t < 128) {
        const int q = t - 32, d = q >> 5, f = q & 31;
        const int col = 32 + q;   // T1 col for P[d,f]
        float a = mR_b[f] * T1[20 * 128 + col];
        #pragma unroll
        for (int e = 0; e < 20; ++e) a = fmaf(mR_w[e * 96 + f], T1[e * 128 + col], a);
        float c = mR_b[64 + f] * T2[(60 + d) * 32 + f];
        #pragma unroll
        for (int e = 0; e < 20; ++e) c = fmaf(mR_w[e * 96 + 64 + f], T2[(d * 20 + e) * 32 + f], c);
        vnew[q] = vector[i * 96 + q] + a + c;
    }
    __syncthreads();

    // ---- update phase ----
    if (t < 96) {
        const int d = t >> 5, f = t & 31;
        float au = 0.f, av = 0.f;
        #pragma unroll
        for (int k = 0; k < 32; ++k) {
            const float vv = vnew[d * 32 + k];
            au = fmaf(vv, U_w[k * 32 + f], au);
            av = fmaf(vv, V_w[k * 32 + f], av);
        }
        lUs[t] = au; rVs[t] = av;
    }
    __syncthreads();
    if (t < 32)
        rnorm[t] = sqrtf(rVs[t] * rVs[t] + rVs[32 + t] * rVs[32 + t] + rVs[64 + t] * rVs[64 + t]);
    __syncthreads();
    if (t < 32) {
        float a = uR_b1[t];
        #pragma unroll
        for (int k = 0; k < 32; ++k) a = fmaf(snew[k], uR_w1[k * 32 + t], a);
        #pragma unroll
        for (int k = 0; k < 32; ++k) a = fmaf(rnorm[k], uR_w1[(32 + k) * 32 + t], a);
        h2s[t] = silu_f(a);
    }
    __syncthreads();
    if (t < 96) {
        float a = uR_b2[t];
        #pragma unroll
        for (int k = 0; k < 32; ++k) a = fmaf(h2s[k], uR_w2[k * 96 + t], a);
        f2s[t] = a;
    }
    __syncthreads();
    if (t < 32) {
        const float inner = lUs[t] * rVs[t] + lUs[32 + t] * rVs[32 + t] + lUs[64 + t] * rVs[64 + t];
        out[i * 32 + t] = snew[t] + inner * f2s[32 + t] + f2s[64 + t];
    }
    if (t < 96) {
        out[32768 + i * 96 + t] = vnew[t] + f2s[t & 31] * lUs[t];
    }
}

extern "C" void kernel_launch(void* const* d_in, const int* in_sizes, int n_in,
                              void* d_out, int out_size, void* d_ws, size_t ws_size,
                              hipStream_t stream) {
    const float* scalar    = (const float*)d_in[0];
    const float* vector    = (const float*)d_in[1];
    const float* expansion = (const float*)d_in[2];
    const float* direction = (const float*)d_in[3];
    const float* mask      = (const float*)d_in[4];
    const float* mL_w1     = (const float*)d_in[5];
    const float* mL_b1     = (const float*)d_in[6];
    const float* mL_w2     = (const float*)d_in[7];
    const float* mL_b2     = (const float*)d_in[8];
    const float* mR_w      = (const float*)d_in[9];
    const float* mR_b      = (const float*)d_in[10];
    const float* uR_w1     = (const float*)d_in[11];
    const float* uR_b1     = (const float*)d_in[12];
    const float* uR_w2     = (const float*)d_in[13];
    const float* uR_b2     = (const float*)d_in[14];
    const float* U_w       = (const float*)d_in[15];
    const float* V_w       = (const float*)d_in[16];
    float* out = (float*)d_out;
    unsigned short* RT = (unsigned short*)d_ws;   // 160*1024*2 = 320 KB

    hipLaunchKernelGGL(node_kernel, dim3(NN), dim3(128), 0, stream,
                       scalar, vector, mL_w1, mL_b1, mL_w2, mL_b2, RT);
    hipLaunchKernelGGL(edge_mfma_kernel, dim3(NN), dim3(128), 0, stream,
                       scalar, vector, expansion, direction, mask,
                       mR_w, mR_b, uR_w1, uR_b1, uR_w2, uR_b2, U_w, V_w,
                       RT, out);
}